// Round 6
// baseline (522.487 us; speedup 1.0000x reference)
//
#include <hip/hip_runtime.h>
#include <hip/hip_bf16.h>

#define N_ROWS 8192
#define D_DIM  256

// loss_i = log(sum_{j != i} exp(<x_i,y_j>/T)) - <x_i,y_i>/T ; out = mean_i loss_i
// fp8 e4m3 inputs (scale 64), PLAIN row-major; acc = 4096*<x,y> via MX-scaled
// MFMA 16x16x128 with unit E8M0 scales (exact fp8 dot); 1/4096 in constants.
static constexpr float kQuantScale = 64.0f;
static constexpr float kScaleAcc = 20.609929155556627f / 4096.0f;  // (1/T)*log2(e)/4096
static constexpr float kInvTAcc  = 14.285714285714286f / 4096.0f;  // (1/T)/4096

typedef float f32x4 __attribute__((ext_vector_type(4)));
typedef int   i32x4 __attribute__((ext_vector_type(4)));
typedef int   i32x8 __attribute__((ext_vector_type(8)));

#define WAITV(n) asm volatile("s_waitcnt vmcnt(" #n ")" ::: "memory")

// async 16B global->LDS: LDS dest = wave-uniform base + lane*16
__device__ __forceinline__ void gl_lds16(const void* g, void* l) {
  __builtin_amdgcn_global_load_lds(
      (const __attribute__((address_space(1))) void*)g,
      (__attribute__((address_space(3))) void*)l, 16, 0, 0);
}

// ---------------- fp32 -> fp8 e4m3 pre-convert (plain layout) + ws init --------
__global__ __launch_bounds__(256)
void cvt_fp8_kernel(const float* __restrict__ x, const float* __restrict__ y,
                    unsigned char* __restrict__ xq, unsigned char* __restrict__ yq,
                    float* __restrict__ rowsum, unsigned int* __restrict__ done,
                    float* __restrict__ out) {
  if (blockIdx.x == 0) {
    for (int i = threadIdx.x; i < N_ROWS; i += 256) rowsum[i] = 0.f;
    if (threadIdx.x < 32) done[threadIdx.x] = 0u;
    if (threadIdx.x == 32) out[0] = 0.f;
  }
  const int per_mat = N_ROWS * D_DIM / 8;  // 8 elements per thread
  int idx = blockIdx.x * blockDim.x + threadIdx.x;
  const float* src = x;
  unsigned char* dst = xq;
  int i = idx;
  if (idx >= per_mat) { src = y; dst = yq; i = idx - per_mat; }
  float4 a = ((const float4*)src)[2 * (size_t)i];
  float4 b = ((const float4*)src)[2 * (size_t)i + 1];
  int v0 = 0, v1 = 0;
  v0 = __builtin_amdgcn_cvt_pk_fp8_f32(a.x * kQuantScale, a.y * kQuantScale, v0, false);
  v0 = __builtin_amdgcn_cvt_pk_fp8_f32(a.z * kQuantScale, a.w * kQuantScale, v0, true);
  v1 = __builtin_amdgcn_cvt_pk_fp8_f32(b.x * kQuantScale, b.y * kQuantScale, v1, false);
  v1 = __builtin_amdgcn_cvt_pk_fp8_f32(b.z * kQuantScale, b.w * kQuantScale, v1, true);
  *(int2*)(dst + (size_t)i * 8) = make_int2(v0, v1);   // plain row-major
}

// ---------------- persistent fused GEMM(MX-fp8) + exp + row-sum + finalize -----
// R22 structure (T3+T4+T5 phase template), R23 FIX:
// R22's counters (FETCH 160 MB, WRITE 169 MB, near-symmetric) = scratch-spill
// round-trips. Cause: diag extraction indexed acc[wn*2+nt] with RUNTIME wn
// (rule #20: runtime-indexed ext_vector arrays demote to local memory), so
// the whole accumulator lived in scratch. R23 makes the index static by
// branching on wave-uniform wn. No other change — clean A/B of the phase
// structure itself.
// Structure recap:
//  - 256 blocks (1/CU), 512 thr, block = 256 rows x 1024 cols (gj group).
//  - Y in 16 tiles of 64 cols, QUAD-buffered (Xs 64K + Ys 4x16K = 128K LDS).
//  - Per tile, 2 phases (one per MX k-block of 128):
//      {ds_read frags ; [kb0: issue stage(tt+3)] ; sched_barrier ;
//       s_barrier ; setprio(1) ; 8 MFMA ; setprio(0) ; s_barrier}
//  - COUNTED vmcnt: one s_waitcnt vmcnt(4) per tile (leaves 2 future tiles'
//    4 loads in flight across barriers); vmcnt(2)/(0) only in drain tail;
//    raw s_barrier in-loop (no __syncthreads vmcnt(0) drain).
//  - Epilogue (exp2+psum+diag+acc-zero, register-only) at tile-top, after
//    the closing barrier, BEFORE next reads.
// WAR safety: buf written at tile tt was last read at tile tt-1; those
// ds_reads retired before tt-1's MFMAs, which precede the barrier the write
// follows. Counted-vmcnt safety: vmcnt retires oldest-first, so tile tt+1's
// loads (always oldest) are covered by any wait to <=4; diag atomics only
// make the wait stricter. Single-ticket finalize (R15-proven, ticket==255).
__global__ __launch_bounds__(512, 1)
void infonce_gemm(const unsigned char* __restrict__ X,
                  const unsigned char* __restrict__ Y,
                  float* __restrict__ rowsum, float* __restrict__ diag,
                  unsigned int* __restrict__ done, float* __restrict__ out) {
  __shared__ unsigned char Xs[256 * 256];      // 64 KB, X-block full-K
  __shared__ unsigned char Ys[4][64 * 256];    // 4 x 16 KB, Y tile quad-buf
  __shared__ unsigned int ticket_s;

  const int b  = blockIdx.x;        // 0..255
  const int bi = b >> 3;            // 0..31: X-row-block (256 rows)
  const int gj = b & 7;             // col-group: 1024 cols = 16 tiles of 64

  const int t    = threadIdx.x;
  const int lane = t & 63;
  const int wave = t >> 6;        // 0..7
  const int wm   = wave >> 1;     // 0..3  (64-row band)
  const int wn   = wave & 1;      // 0..1  (32-col half of 64-col tile)
  const int quad = lane >> 4;     // 0..3
  const int l15  = lane & 15;

  const unsigned char* Xblk = X + (size_t)(bi * 256) * D_DIM;

  // stage one 64-col Y tile (1024 slots of 16B, 2 per thread) into buf
  auto stageY = [&](int tile, int buf) {
#pragma unroll
    for (int it = 0; it < 2; ++it) {
      const int c0  = (it * 8 + wave) * 64;
      const int s   = c0 + lane;
      const int row = s >> 4;                 // 0..63
      const int cg  = (s & 15) ^ (row & 15);  // inverse swizzle on global side
      gl_lds16(Y + (size_t)(gj * 1024 + tile * 64 + row) * D_DIM + cg * 16,
               &Ys[buf][c0 * 16]);
    }
  };

  // ---- prologue: stage X (4096 slots, 8/thread) + Y tiles 0,1,2 ----
#pragma unroll
  for (int it = 0; it < 8; ++it) {
    const int c0  = (it * 8 + wave) * 64;
    const int s   = c0 + lane;
    const int row = s >> 4;                 // 0..255
    const int cg  = (s & 15) ^ (row & 15);
    gl_lds16(Xblk + (size_t)row * D_DIM + cg * 16, &Xs[c0 * 16]);
  }
  stageY(0, 0);
  stageY(1, 1);
  stageY(2, 2);
  WAITV(4);                            // X + Y0 landed; Y1,Y2 (4 loads) in flight
  __builtin_amdgcn_s_barrier();

  f32x4 acc[4][2];
#pragma unroll
  for (int a = 0; a < 4; ++a)
#pragma unroll
    for (int c = 0; c < 2; ++c) acc[a][c] = (f32x4){0.f, 0.f, 0.f, 0.f};

  float psum[4][4];
#pragma unroll
  for (int a = 0; a < 4; ++a)
#pragma unroll
    for (int c = 0; c < 4; ++c) psum[a][c] = 0.f;

  // register-only epilogue for tile rt: exp2+psum, diagonal, acc re-zero.
  // ALL acc indices compile-time constant (rule #20): branch on uniform wn.
  auto do_epilogue = [&](const int rt) {
#pragma unroll
    for (int mt = 0; mt < 4; ++mt) {
#pragma unroll
      for (int rr = 0; rr < 4; ++rr) {
        psum[mt][rr] += __builtin_amdgcn_exp2f(acc[mt][0][rr] * kScaleAcc)
                      + __builtin_amdgcn_exp2f(acc[mt][1][rr] * kScaleAcc);
      }
    }
    // diagonal: cols of tile rt are global (gj*16+rt)*64; they hit this
    // block's rows iff h = gj*16+rt-4*bi in [0,4), on wave band wm==h.
    // Then mt = wn*2+nt and l15 == quad*4+rr.
    const int h = gj * 16 + rt - 4 * bi;
    if (h >= 0 && h < 4 && wm == h) {
      const int gb = bi * 256 + wm * 64;
      if (wn == 0) {
#pragma unroll
        for (int nt = 0; nt < 2; ++nt)
#pragma unroll
          for (int rr = 0; rr < 4; ++rr)
            if (l15 == quad * 4 + rr)
              atomicExch(&diag[gb + nt * 16 + l15], acc[nt][nt][rr]);
      } else {
#pragma unroll
        for (int nt = 0; nt < 2; ++nt)
#pragma unroll
          for (int rr = 0; rr < 4; ++rr)
            if (l15 == quad * 4 + rr)
              atomicExch(&diag[gb + (2 + nt) * 16 + l15], acc[2 + nt][nt][rr]);
      }
    }
#pragma unroll
    for (int a = 0; a < 4; ++a)
#pragma unroll
      for (int c = 0; c < 2; ++c) acc[a][c] = (f32x4){0.f, 0.f, 0.f, 0.f};
  };

#pragma unroll
  for (int tt = 0; tt < 16; ++tt) {
    const int buf = tt & 3;

    if (tt > 0) do_epilogue(tt - 1);   // after prev closing barrier, before reads

#pragma unroll
    for (int kb = 0; kb < 2; ++kb) {
      i32x8 a8[4], b8[2];
#pragma unroll
      for (int mt = 0; mt < 4; ++mt) {
        const int row = wm * 64 + mt * 16 + l15;
        const int p0  = (kb * 8 + quad * 2) ^ (row & 15);
        i32x4 lo = *(const i32x4*)(&Xs[row * 256 + p0 * 16]);
        i32x4 hi = *(const i32x4*)(&Xs[row * 256 + (p0 ^ 1) * 16]);
        a8[mt] = __builtin_shufflevector(lo, hi, 0, 1, 2, 3, 4, 5, 6, 7);
      }
#pragma unroll
      for (int nt = 0; nt < 2; ++nt) {
        const int row = wn * 32 + nt * 16 + l15;
        const int p0  = (kb * 8 + quad * 2) ^ (row & 15);
        i32x4 lo = *(const i32x4*)(&Ys[buf][row * 256 + p0 * 16]);
        i32x4 hi = *(const i32x4*)(&Ys[buf][row * 256 + (p0 ^ 1) * 16]);
        b8[nt] = __builtin_shufflevector(lo, hi, 0, 1, 2, 3, 4, 5, 6, 7);
      }

      if (kb == 0 && tt + 3 < 16) stageY(tt + 3, (tt + 3) & 3);

      __builtin_amdgcn_sched_barrier(0);   // pin reads+stage before the barrier
      __builtin_amdgcn_s_barrier();

      __builtin_amdgcn_s_setprio(1);
#pragma unroll
      for (int mt = 0; mt < 4; ++mt)
#pragma unroll
        for (int nt = 0; nt < 2; ++nt)
          acc[mt][nt] = __builtin_amdgcn_mfma_scale_f32_16x16x128_f8f6f4(
              a8[mt], b8[nt], acc[mt][nt],
              0, 0,                    // cbsz=fp8 e4m3, blgp=fp8 e4m3
              0, 0x7F7F7F7F,           // A scales = 1.0 (E8M0 127)
              0, 0x7F7F7F7F);          // B scales = 1.0
      __builtin_amdgcn_s_setprio(0);

      if (kb == 0) {
        __builtin_amdgcn_s_barrier();
      } else {
        // counted drain: ensure tile tt+1 landed; keep future tiles in flight
        if (tt <= 12)      { WAITV(4); }
        else if (tt == 13) { WAITV(2); }
        else if (tt == 14) { WAITV(0); }
        if (tt < 15) __builtin_amdgcn_s_barrier();
      }
    }
  }

  do_epilogue(15);

  // ---- one reduce + flush per block (8 shfl-chains + 8 atomics per wave) ----
  {
    const int gi_base = bi * 256 + wm * 64;
#pragma unroll
    for (int mt = 0; mt < 4; ++mt) {
#pragma unroll
      for (int rr = 0; rr < 4; ++rr) {
        float v = psum[mt][rr];
        v += __shfl_xor(v, 1);
        v += __shfl_xor(v, 2);
        v += __shfl_xor(v, 4);
        v += __shfl_xor(v, 8);
        if (l15 == 0)
          atomicAdd(&rowsum[gi_base + mt * 16 + quad * 4 + rr], v);
      }
    }
  }

  // ---- last-block finalize (single fence, single ticket — R15-proven) ----
  __syncthreads();                       // drains this block's atomics (vmcnt)
  if (t == 0) ticket_s = atomicAdd(&done[0], 1u);
  __syncthreads();
  if (ticket_s == 255u) {
    __threadfence();                     // one acquire, one block only
    float local = 0.f;
    for (int i = t; i < N_ROWS; i += 512) {
      const float rs = atomicAdd(&rowsum[i], 0.0f);   // device-coherent read
      const float d  = atomicAdd(&diag[i], 0.0f);
      local += __logf(rs - __builtin_amdgcn_exp2f(d * kScaleAcc)) - d * kInvTAcc;
    }
    float* red = (float*)Xs;             // Xs dead after last round; reuse
    red[t] = local;
    __syncthreads();
    for (int s2 = 256; s2 > 0; s2 >>= 1) {
      if (t < s2) red[t] += red[t + s2];
      __syncthreads();
    }
    if (t == 0) out[0] = red[0] / (float)N_ROWS;
  }
}

extern "C" void kernel_launch(void* const* d_in, const int* in_sizes, int n_in,
                              void* d_out, int out_size, void* d_ws, size_t ws_size,
                              hipStream_t stream) {
  const float* x = (const float*)d_in[0];
  const float* y = (const float*)d_in[1];
  float* out = (float*)d_out;

  // ws layout: rowsum[N] f32 | diag[N] f32 | done[32] u32 (128 B) | xq | yq
  float* rowsum = (float*)d_ws;
  float* diag   = rowsum + N_ROWS;
  unsigned int* done = (unsigned int*)(diag + N_ROWS);
  unsigned char* xq = (unsigned char*)d_ws + 2 * N_ROWS * sizeof(float) + 128;
  unsigned char* yq = xq + (size_t)N_ROWS * D_DIM;

  int cvt_blocks = 2 * N_ROWS * D_DIM / 8 / 256;  // 2048
  cvt_fp8_kernel<<<cvt_blocks, 256, 0, stream>>>(x, y, xq, yq, rowsum, done, out);

  infonce_gemm<<<256, 512, 0, stream>>>(xq, yq, rowsum, diag, done, out);
}

// Round 8
// 121.314 us; speedup vs baseline: 4.3069x; 4.3069x over previous
//
#include <hip/hip_runtime.h>
#include <hip/hip_bf16.h>

#define N_ROWS 8192
#define D_DIM  256

// loss_i = log(sum_{j != i} exp(<x_i,y_j>/T)) - <x_i,y_i>/T ; out = mean_i loss_i
// fp8 e4m3 inputs (scale 64), PLAIN row-major; acc = 4096*<x,y> via MX-scaled
// MFMA 16x16x128 with unit E8M0 scales (exact fp8 dot); 1/4096 in constants.
static constexpr float kQuantScale = 64.0f;
static constexpr float kScaleAcc = 20.609929155556627f / 4096.0f;  // (1/T)*log2(e)/4096
static constexpr float kInvTAcc  = 14.285714285714286f / 4096.0f;  // (1/T)/4096

typedef float f32x4 __attribute__((ext_vector_type(4)));
typedef int   i32x4 __attribute__((ext_vector_type(4)));
typedef int   i32x8 __attribute__((ext_vector_type(8)));

// ---------------- fp32 -> fp8 e4m3 pre-convert (plain layout) + ws init --------
__global__ __launch_bounds__(256)
void cvt_fp8_kernel(const float* __restrict__ x, const float* __restrict__ y,
                    unsigned char* __restrict__ xq, unsigned char* __restrict__ yq,
                    float* __restrict__ rowsum, unsigned int* __restrict__ done,
                    float* __restrict__ out) {
  if (blockIdx.x == 0) {
    for (int i = threadIdx.x; i < N_ROWS; i += 256) rowsum[i] = 0.f;
    if (threadIdx.x < 32) done[threadIdx.x] = 0u;
    if (threadIdx.x == 32) out[0] = 0.f;
  }
  const int per_mat = N_ROWS * D_DIM / 8;  // 8 elements per thread
  int idx = blockIdx.x * blockDim.x + threadIdx.x;
  const float* src = x;
  unsigned char* dst = xq;
  int i = idx;
  if (idx >= per_mat) { src = y; dst = yq; i = idx - per_mat; }
  float4 a = ((const float4*)src)[2 * (size_t)i];
  float4 b = ((const float4*)src)[2 * (size_t)i + 1];
  int v0 = 0, v1 = 0;
  v0 = __builtin_amdgcn_cvt_pk_fp8_f32(a.x * kQuantScale, a.y * kQuantScale, v0, false);
  v0 = __builtin_amdgcn_cvt_pk_fp8_f32(a.z * kQuantScale, a.w * kQuantScale, v0, true);
  v1 = __builtin_amdgcn_cvt_pk_fp8_f32(b.x * kQuantScale, b.y * kQuantScale, v1, false);
  v1 = __builtin_amdgcn_cvt_pk_fp8_f32(b.z * kQuantScale, b.w * kQuantScale, v1, true);
  *(int2*)(dst + (size_t)i * 8) = make_int2(v0, v1);   // plain row-major
}

// ---------------- barrier-free fused GEMM(MX-fp8) + exp + row-sum + finalize ---
// R24/R25 REDESIGN (R24 never measured — container failure; resubmitted):
// NO LDS STAGING, NO MID-KERNEL BARRIERS.
// Evidence: R17 counters (MfmaUtil 13, VALUBusy 19, HBM 3%, conflicts 0) =
// latency/convoy-bound; R21 (2 blocks/CU) neutral; R22/R23 (phase template)
// allocator-hostile (scratch spill). X and Y are 2 MB each as fp8 — BOTH fit
// per-XCD L2 (4 MB), so LDS staging is pure overhead (guide Common-mistake
// #7: stage only when data doesn't cache-fit). Dropping it removes barriers,
// vmcnt drains, and staging address-VALU entirely; waves run free.
// Geometry: 1024 blocks x 256 thr (4 waves). Block = 64 rows x 1024 cols.
//   Wave w sweeps 4 sequential 64x64 tiles (cols bC*1024 + w*256 + jt*64).
//   Fragments loaded straight from global (L1/L2): A-tile 16 KB shared by
//   all 4 waves (L1-hot); B streamed once per block (256 KB) from L2.
//   Device L2 traffic ~272 MB (~8 us at 34.5 TB/s) overlapping MFMA 7.4 us.
// Fragment mapping = R15/R17-VERIFIED 16x16x128: lane l15 = row, quad picks
// the 32B chunk of the kb's 128B window; C/D: col=l15, row=quad*4+rr.
// psum in regs across sweep; one LDS[64] block-reduce + 64 global atomics
// per block (65k total). Diag + single-ticket finalize patterns unchanged.
__global__ __launch_bounds__(256)
void infonce_gemm(const unsigned char* __restrict__ X,
                  const unsigned char* __restrict__ Y,
                  float* __restrict__ rowsum, float* __restrict__ diag,
                  unsigned int* __restrict__ done, float* __restrict__ out) {
  __shared__ float sm[64];        // per-block row-sum reduce
  __shared__ float red[256];      // finalize reduce
  __shared__ unsigned int ticket_s;

  const int b  = blockIdx.x;      // 0..1023
  const int bR = b >> 3;          // 0..127: 64-row band
  const int bC = b & 7;           // 0..7: 1024-col group

  const int t    = threadIdx.x;
  const int lane = t & 63;
  const int w    = t >> 6;        // 0..3
  const int quad = lane >> 4;     // 0..3
  const int l15  = lane & 15;

  if (t < 64) sm[t] = 0.f;
  __syncthreads();                // zeros visible before any wave's ds-adds

  const int rowbase = bR * 64;
  const unsigned char* Xr = X + (size_t)rowbase * D_DIM;

  float psum[4][4];
#pragma unroll
  for (int a = 0; a < 4; ++a)
#pragma unroll
    for (int c = 0; c < 4; ++c) psum[a][c] = 0.f;

  for (int jt = 0; jt < 4; ++jt) {
    const int cbase = bC * 1024 + w * 256 + jt * 64;
    const unsigned char* Yc = Y + (size_t)cbase * D_DIM;

    f32x4 acc[4][4];
#pragma unroll
    for (int a = 0; a < 4; ++a)
#pragma unroll
      for (int c = 0; c < 4; ++c) acc[a][c] = (f32x4){0.f, 0.f, 0.f, 0.f};

#pragma unroll
    for (int kb = 0; kb < 2; ++kb) {
      i32x8 a8[4], b8[4];
#pragma unroll
      for (int mt = 0; mt < 4; ++mt) {
        const size_t off = (size_t)(mt * 16 + l15) * D_DIM + kb * 128 + quad * 32;
        i32x4 lo = *(const i32x4*)(Xr + off);
        i32x4 hi = *(const i32x4*)(Xr + off + 16);
        a8[mt] = __builtin_shufflevector(lo, hi, 0, 1, 2, 3, 4, 5, 6, 7);
      }
#pragma unroll
      for (int nt = 0; nt < 4; ++nt) {
        const size_t off = (size_t)(nt * 16 + l15) * D_DIM + kb * 128 + quad * 32;
        i32x4 lo = *(const i32x4*)(Yc + off);
        i32x4 hi = *(const i32x4*)(Yc + off + 16);
        b8[nt] = __builtin_shufflevector(lo, hi, 0, 1, 2, 3, 4, 5, 6, 7);
      }
#pragma unroll
      for (int mt = 0; mt < 4; ++mt)
#pragma unroll
        for (int nt = 0; nt < 4; ++nt)
          acc[mt][nt] = __builtin_amdgcn_mfma_scale_f32_16x16x128_f8f6f4(
              a8[mt], b8[nt], acc[mt][nt],
              0, 0,                    // cbsz=fp8 e4m3, blgp=fp8 e4m3
              0, 0x7F7F7F7F,           // A scales = 1.0 (E8M0 127)
              0, 0x7F7F7F7F);          // B scales = 1.0
    }

    // ---- epilogue: exp + accumulate into registers (all indices static) ----
#pragma unroll
    for (int mt = 0; mt < 4; ++mt) {
#pragma unroll
      for (int rr = 0; rr < 4; ++rr) {
        float part = 0.f;
#pragma unroll
        for (int nt = 0; nt < 4; ++nt)
          part += __builtin_amdgcn_exp2f(acc[mt][nt][rr] * kScaleAcc);
        psum[mt][rr] += part;
      }
    }
    // diagonal: this 64x64 tile is on the diagonal iff cbase == rowbase
    // (both 64-aligned; unique (bC,w,jt) per bR). Within it, diag lives in
    // subtiles mt==nt at l15 == quad*4+rr (R17-verified mapping).
    if (cbase == rowbase) {
#pragma unroll
      for (int nt = 0; nt < 4; ++nt)
#pragma unroll
        for (int rr = 0; rr < 4; ++rr)
          if (l15 == quad * 4 + rr)
            atomicExch(&diag[rowbase + nt * 16 + l15], acc[nt][nt][rr]);
    }
  }

  // ---- wave reduce (xor over l15) -> LDS row accumulator ----
#pragma unroll
  for (int mt = 0; mt < 4; ++mt) {
#pragma unroll
    for (int rr = 0; rr < 4; ++rr) {
      float v = psum[mt][rr];
      v += __shfl_xor(v, 1);
      v += __shfl_xor(v, 2);
      v += __shfl_xor(v, 4);
      v += __shfl_xor(v, 8);
      if (l15 == 0)
        atomicAdd(&sm[mt * 16 + quad * 4 + rr], v);   // LDS atomic, 4 waves
    }
  }
  __syncthreads();
  if (t < 64) atomicAdd(&rowsum[rowbase + t], sm[t]); // 64 global atomics/block

  // ---- last-block finalize (single fence, single ticket — R15-proven) ----
  __syncthreads();                       // drains this block's atomics (vmcnt)
  if (t == 0) ticket_s = atomicAdd(&done[0], 1u);
  __syncthreads();
  if (ticket_s == 1023u) {
    __threadfence();                     // one acquire, one block only
    float local = 0.f;
    for (int i = t; i < N_ROWS; i += 256) {
      const float rs = atomicAdd(&rowsum[i], 0.0f);   // device-coherent read
      const float d  = atomicAdd(&diag[i], 0.0f);
      local += __logf(rs - __builtin_amdgcn_exp2f(d * kScaleAcc)) - d * kInvTAcc;
    }
    red[t] = local;
    __syncthreads();
    for (int s2 = 128; s2 > 0; s2 >>= 1) {
      if (t < s2) red[t] += red[t + s2];
      __syncthreads();
    }
    if (t == 0) out[0] = red[0] / (float)N_ROWS;
  }
}

extern "C" void kernel_launch(void* const* d_in, const int* in_sizes, int n_in,
                              void* d_out, int out_size, void* d_ws, size_t ws_size,
                              hipStream_t stream) {
  const float* x = (const float*)d_in[0];
  const float* y = (const float*)d_in[1];
  float* out = (float*)d_out;

  // ws layout: rowsum[N] f32 | diag[N] f32 | done[32] u32 (128 B) | xq | yq
  float* rowsum = (float*)d_ws;
  float* diag   = rowsum + N_ROWS;
  unsigned int* done = (unsigned int*)(diag + N_ROWS);
  unsigned char* xq = (unsigned char*)d_ws + 2 * N_ROWS * sizeof(float) + 128;
  unsigned char* yq = xq + (size_t)N_ROWS * D_DIM;

  int cvt_blocks = 2 * N_ROWS * D_DIM / 8 / 256;  // 2048
  cvt_fp8_kernel<<<cvt_blocks, 256, 0, stream>>>(x, y, xq, yq, rowsum, done, out);

  infonce_gemm<<<1024, 256, 0, stream>>>(xq, yq, rowsum, diag, done, out);
}

// Round 9
// 101.714 us; speedup vs baseline: 5.1368x; 1.1927x over previous
//
#include <hip/hip_runtime.h>
#include <hip/hip_bf16.h>

#define N_ROWS 8192
#define D_DIM  256

// loss_i = log(sum_{j != i} exp(<x_i,y_j>/T)) - <x_i,y_i>/T ; out = mean_i loss_i
// fp8 e4m3 inputs (scale 64), PLAIN row-major; acc = 4096*<x,y> via MX-scaled
// MFMA 16x16x128 with unit E8M0 scales (exact fp8 dot); 1/4096 in constants.
static constexpr float kQuantScale = 64.0f;
static constexpr float kScaleAcc = 20.609929155556627f / 4096.0f;  // (1/T)*log2(e)/4096
static constexpr float kInvTAcc  = 14.285714285714286f / 4096.0f;  // (1/T)/4096

typedef float f32x4 __attribute__((ext_vector_type(4)));
typedef int   i32x4 __attribute__((ext_vector_type(4)));
typedef int   i32x8 __attribute__((ext_vector_type(8)));

#define WAITV(n) asm volatile("s_waitcnt vmcnt(" #n ")" ::: "memory")

// async 16B global->LDS: LDS dest = wave-uniform base + lane*16
__device__ __forceinline__ void gl_lds16(const void* g, void* l) {
  __builtin_amdgcn_global_load_lds(
      (const __attribute__((address_space(1))) void*)g,
      (__attribute__((address_space(3))) void*)l, 16, 0, 0);
}

// ---------------- fp32 -> fp8 e4m3 pre-convert (plain layout) + ws init --------
__global__ __launch_bounds__(256)
void cvt_fp8_kernel(const float* __restrict__ x, const float* __restrict__ y,
                    unsigned char* __restrict__ xq, unsigned char* __restrict__ yq,
                    float* __restrict__ rowsum, unsigned int* __restrict__ done,
                    float* __restrict__ out) {
  if (blockIdx.x == 0) {
    for (int i = threadIdx.x; i < N_ROWS; i += 256) rowsum[i] = 0.f;
    if (threadIdx.x < 32) done[threadIdx.x] = 0u;
    if (threadIdx.x == 32) out[0] = 0.f;
  }
  const int per_mat = N_ROWS * D_DIM / 8;  // 8 elements per thread
  int idx = blockIdx.x * blockDim.x + threadIdx.x;
  const float* src = x;
  unsigned char* dst = xq;
  int i = idx;
  if (idx >= per_mat) { src = y; dst = yq; i = idx - per_mat; }
  float4 a = ((const float4*)src)[2 * (size_t)i];
  float4 b = ((const float4*)src)[2 * (size_t)i + 1];
  int v0 = 0, v1 = 0;
  v0 = __builtin_amdgcn_cvt_pk_fp8_f32(a.x * kQuantScale, a.y * kQuantScale, v0, false);
  v0 = __builtin_amdgcn_cvt_pk_fp8_f32(a.z * kQuantScale, a.w * kQuantScale, v0, true);
  v1 = __builtin_amdgcn_cvt_pk_fp8_f32(b.x * kQuantScale, b.y * kQuantScale, v1, false);
  v1 = __builtin_amdgcn_cvt_pk_fp8_f32(b.z * kQuantScale, b.w * kQuantScale, v1, true);
  *(int2*)(dst + (size_t)i * 8) = make_int2(v0, v1);   // plain row-major
}

// ---------------- persistent fused GEMM(MX-fp8) + exp + row-sum + finalize -----
// R25 = R23's SCHEDULE without R23's ENCODING poison.
// R23 spilled 6 KB/thread (WRITE 787 MB): fully-unrolled 16-tile loop +
// sched_barrier(0) pinning at 32 boundaries kept all phases' fragments live.
// The counted-vmcnt quad-buffer schedule itself was never falsified, and its
// compute body is verified (R23 absmax=0). R25 re-encodes it register-
// friendly:
//  - DYNAMIC tile loop (#pragma unroll 1) — compact codegen, low pressure.
//  - NO sched_barrier. setprio(1/0) around MFMA cluster only (T5).
//  - 256 blocks (1/CU), 512 thr; block = 256 rows x 1024 cols.
//  - Y: 16 tiles of 64 cols, quad-buffered (Xs 64K + 4x16K = 128K LDS),
//    staged 3-ahead via global_load_lds.
//  - ONE counted wait + ONE raw s_barrier per tile: vmcnt(4) keeps the two
//    future tiles' 4 loads in flight (never vmcnt(0) mid-loop — that drain,
//    forced by __syncthreads, is R17's per-round convoy).
// WAR safety: buf (tt+3)&3 was last read at tile tt-1; all waves' reads
// retired before the tt-1 end barrier, and the stage is issued after it.
// Counted-vmcnt safety: vmcnt retires oldest-first; waiting to 4 at tile tt
// guarantees tile tt+1's 2 loads (oldest in flight) landed; every wave waits
// for its own loads, the barrier makes it collective.
__global__ __launch_bounds__(512, 1)
void infonce_gemm(const unsigned char* __restrict__ X,
                  const unsigned char* __restrict__ Y,
                  float* __restrict__ rowsum, float* __restrict__ diag,
                  unsigned int* __restrict__ done, float* __restrict__ out) {
  __shared__ unsigned char Xs[256 * 256];      // 64 KB, X-block full-K
  __shared__ unsigned char Ys[4][64 * 256];    // 4 x 16 KB, Y tile quad-buf
  __shared__ unsigned int ticket_s;

  const int b  = blockIdx.x;        // 0..255
  const int bi = b >> 3;            // 0..31: X-row-block (256 rows)
  const int gj = b & 7;             // col-group: 1024 cols = 16 tiles of 64

  const int t    = threadIdx.x;
  const int lane = t & 63;
  const int wave = t >> 6;        // 0..7
  const int wm   = wave >> 1;     // 0..3  (64-row band)
  const int wn   = wave & 1;      // 0..1  (32-col half of 64-col tile)
  const int quad = lane >> 4;     // 0..3
  const int l15  = lane & 15;

  const unsigned char* Xblk = X + (size_t)(bi * 256) * D_DIM;

  // stage one 64-col Y tile (1024 slots of 16B, 2 per thread) into buf
  auto stageY = [&](int tile, int buf) {
#pragma unroll
    for (int it = 0; it < 2; ++it) {
      const int c0  = (it * 8 + wave) * 64;
      const int s   = c0 + lane;
      const int row = s >> 4;                 // 0..63
      const int cg  = (s & 15) ^ (row & 15);  // inverse swizzle on global side
      gl_lds16(Y + (size_t)(gj * 1024 + tile * 64 + row) * D_DIM + cg * 16,
               &Ys[buf][c0 * 16]);
    }
  };

  // ---- prologue: stage X (4096 slots, 8/thread) + Y tiles 0,1,2 ----
#pragma unroll
  for (int it = 0; it < 8; ++it) {
    const int c0  = (it * 8 + wave) * 64;
    const int s   = c0 + lane;
    const int row = s >> 4;                 // 0..255
    const int cg  = (s & 15) ^ (row & 15);
    gl_lds16(Xblk + (size_t)row * D_DIM + cg * 16, &Xs[c0 * 16]);
  }
  stageY(0, 0);
  stageY(1, 1);
  stageY(2, 2);
  WAITV(4);                            // X + Y0 landed; Y1,Y2 (4 loads) in flight
  __builtin_amdgcn_s_barrier();
  asm volatile("" ::: "memory");

  f32x4 acc[4][2];
#pragma unroll
  for (int a = 0; a < 4; ++a)
#pragma unroll
    for (int c = 0; c < 2; ++c) acc[a][c] = (f32x4){0.f, 0.f, 0.f, 0.f};

  float psum[4][4];
#pragma unroll
  for (int a = 0; a < 4; ++a)
#pragma unroll
    for (int c = 0; c < 4; ++c) psum[a][c] = 0.f;

#pragma unroll 1
  for (int tt = 0; tt < 16; ++tt) {
    const int buf = tt & 3;

    if (tt + 3 < 16) stageY(tt + 3, (tt + 3) & 3);   // issue early (T3 recipe)

    // full-K compute from Ys[buf]: 2 MX k-blocks; per kb: 6 b128-pairs + 8 MFMA
#pragma unroll
    for (int kb = 0; kb < 2; ++kb) {
      i32x8 a8[4], b8[2];
#pragma unroll
      for (int mt = 0; mt < 4; ++mt) {
        const int row = wm * 64 + mt * 16 + l15;
        const int p0  = (kb * 8 + quad * 2) ^ (row & 15);
        i32x4 lo = *(const i32x4*)(&Xs[row * 256 + p0 * 16]);
        i32x4 hi = *(const i32x4*)(&Xs[row * 256 + (p0 ^ 1) * 16]);
        a8[mt] = __builtin_shufflevector(lo, hi, 0, 1, 2, 3, 4, 5, 6, 7);
      }
#pragma unroll
      for (int nt = 0; nt < 2; ++nt) {
        const int row = wn * 32 + nt * 16 + l15;
        const int p0  = (kb * 8 + quad * 2) ^ (row & 15);
        i32x4 lo = *(const i32x4*)(&Ys[buf][row * 256 + p0 * 16]);
        i32x4 hi = *(const i32x4*)(&Ys[buf][row * 256 + (p0 ^ 1) * 16]);
        b8[nt] = __builtin_shufflevector(lo, hi, 0, 1, 2, 3, 4, 5, 6, 7);
      }
      __builtin_amdgcn_s_setprio(1);
#pragma unroll
      for (int mt = 0; mt < 4; ++mt)
#pragma unroll
        for (int nt = 0; nt < 2; ++nt)
          acc[mt][nt] = __builtin_amdgcn_mfma_scale_f32_16x16x128_f8f6f4(
              a8[mt], b8[nt], acc[mt][nt],
              0, 0,                    // cbsz=fp8 e4m3, blgp=fp8 e4m3
              0, 0x7F7F7F7F,           // A scales = 1.0 (E8M0 127)
              0, 0x7F7F7F7F);          // B scales = 1.0
      __builtin_amdgcn_s_setprio(0);
    }

    // ---- epilogue (register-only; runs while future stages fly) ----
#pragma unroll
    for (int mt = 0; mt < 4; ++mt) {
#pragma unroll
      for (int rr = 0; rr < 4; ++rr) {
        psum[mt][rr] += __builtin_amdgcn_exp2f(acc[mt][0][rr] * kScaleAcc)
                      + __builtin_amdgcn_exp2f(acc[mt][1][rr] * kScaleAcc);
      }
    }
    // diagonal (R23-verified): cols of tile tt hit this block's rows iff
    // h = gj*16+tt-4*bi in [0,4) on wave band wm==h; then mt = wn*2+nt and
    // l15 == quad*4+rr. All acc indices compile-time (branch on uniform wn).
    {
      const int h = gj * 16 + tt - 4 * bi;
      if (h >= 0 && h < 4 && wm == h) {
        const int gb = bi * 256 + wm * 64;
        if (wn == 0) {
#pragma unroll
          for (int nt = 0; nt < 2; ++nt)
#pragma unroll
            for (int rr = 0; rr < 4; ++rr)
              if (l15 == quad * 4 + rr)
                atomicExch(&diag[gb + nt * 16 + l15], acc[nt][nt][rr]);
        } else {
#pragma unroll
          for (int nt = 0; nt < 2; ++nt)
#pragma unroll
            for (int rr = 0; rr < 4; ++rr)
              if (l15 == quad * 4 + rr)
                atomicExch(&diag[gb + (2 + nt) * 16 + l15], acc[2 + nt][nt][rr]);
        }
      }
    }
#pragma unroll
    for (int a = 0; a < 4; ++a)
#pragma unroll
      for (int c = 0; c < 2; ++c) acc[a][c] = (f32x4){0.f, 0.f, 0.f, 0.f};

    // ---- one counted wait + one barrier per tile (never vmcnt(0) mid-loop) --
    if (tt <= 12)      { WAITV(4); }   // tile tt+1 landed; tt+2,tt+3 in flight
    else if (tt == 13) { WAITV(2); }   // tile 14 landed; 15 in flight
    else if (tt == 14) { WAITV(0); }   // tile 15 landed
    if (tt < 15) {
      __builtin_amdgcn_s_barrier();
      asm volatile("" ::: "memory");
    }
  }

  // ---- one reduce + flush per block (8 shfl-chains + 8 atomics per wave) ----
  {
    const int gi_base = bi * 256 + wm * 64;
#pragma unroll
    for (int mt = 0; mt < 4; ++mt) {
#pragma unroll
      for (int rr = 0; rr < 4; ++rr) {
        float v = psum[mt][rr];
        v += __shfl_xor(v, 1);
        v += __shfl_xor(v, 2);
        v += __shfl_xor(v, 4);
        v += __shfl_xor(v, 8);
        if (l15 == 0)
          atomicAdd(&rowsum[gi_base + mt * 16 + quad * 4 + rr], v);
      }
    }
  }

  // ---- last-block finalize (single fence, single ticket — R15-proven) ----
  __syncthreads();                       // drains this block's atomics (vmcnt)
  if (t == 0) ticket_s = atomicAdd(&done[0], 1u);
  __syncthreads();
  if (ticket_s == 255u) {
    __threadfence();                     // one acquire, one block only
    float local = 0.f;
    for (int i = t; i < N_ROWS; i += 512) {
      const float rs = atomicAdd(&rowsum[i], 0.0f);   // device-coherent read
      const float d  = atomicAdd(&diag[i], 0.0f);
      local += __logf(rs - __builtin_amdgcn_exp2f(d * kScaleAcc)) - d * kInvTAcc;
    }
    float* red = (float*)Xs;             // Xs dead after last tile; reuse
    red[t] = local;
    __syncthreads();
    for (int s2 = 256; s2 > 0; s2 >>= 1) {
      if (t < s2) red[t] += red[t + s2];
      __syncthreads();
    }
    if (t == 0) out[0] = red[0] / (float)N_ROWS;
  }
}

extern "C" void kernel_launch(void* const* d_in, const int* in_sizes, int n_in,
                              void* d_out, int out_size, void* d_ws, size_t ws_size,
                              hipStream_t stream) {
  const float* x = (const float*)d_in[0];
  const float* y = (const float*)d_in[1];
  float* out = (float*)d_out;

  // ws layout: rowsum[N] f32 | diag[N] f32 | done[32] u32 (128 B) | xq | yq
  float* rowsum = (float*)d_ws;
  float* diag   = rowsum + N_ROWS;
  unsigned int* done = (unsigned int*)(diag + N_ROWS);
  unsigned char* xq = (unsigned char*)d_ws + 2 * N_ROWS * sizeof(float) + 128;
  unsigned char* yq = xq + (size_t)N_ROWS * D_DIM;

  int cvt_blocks = 2 * N_ROWS * D_DIM / 8 / 256;  // 2048
  cvt_fp8_kernel<<<cvt_blocks, 256, 0, stream>>>(x, y, xq, yq, rowsum, done, out);

  infonce_gemm<<<256, 512, 0, stream>>>(xq, yq, rowsum, diag, done, out);
}

// Round 10
// 99.598 us; speedup vs baseline: 5.2460x; 1.0212x over previous
//
#include <hip/hip_runtime.h>
#include <hip/hip_bf16.h>

#define N_ROWS 8192
#define D_DIM  256

// loss_i = log(sum_{j != i} exp(<x_i,y_j>/T)) - <x_i,y_i>/T ; out = mean_i loss_i
// fp8 e4m3 inputs (scale 64), PLAIN row-major; acc = 4096*<x,y> via MX-scaled
// MFMA 16x16x128 with unit E8M0 scales (exact fp8 dot); 1/4096 in constants.
static constexpr float kQuantScale = 64.0f;
static constexpr float kScaleAcc = 20.609929155556627f / 4096.0f;  // (1/T)*log2(e)/4096
static constexpr float kInvTAcc  = 14.285714285714286f / 4096.0f;  // (1/T)/4096

typedef float f32x4 __attribute__((ext_vector_type(4)));
typedef int   i32x4 __attribute__((ext_vector_type(4)));
typedef int   i32x8 __attribute__((ext_vector_type(8)));

// async 16B global->LDS: LDS dest = wave-uniform base + lane*16
__device__ __forceinline__ void gl_lds16(const void* g, void* l) {
  __builtin_amdgcn_global_load_lds(
      (const __attribute__((address_space(1))) void*)g,
      (__attribute__((address_space(3))) void*)l, 16, 0, 0);
}

// ---------------- fp32 -> fp8 e4m3 pre-convert (plain layout) + ws init --------
__global__ __launch_bounds__(256)
void cvt_fp8_kernel(const float* __restrict__ x, const float* __restrict__ y,
                    unsigned char* __restrict__ xq, unsigned char* __restrict__ yq,
                    float* __restrict__ rowsum, unsigned int* __restrict__ done,
                    float* __restrict__ out) {
  if (blockIdx.x == 0) {
    for (int i = threadIdx.x; i < N_ROWS; i += 256) rowsum[i] = 0.f;
    if (threadIdx.x < 32) done[threadIdx.x] = 0u;
    if (threadIdx.x == 32) out[0] = 0.f;
  }
  const int per_mat = N_ROWS * D_DIM / 8;  // 8 elements per thread
  int idx = blockIdx.x * blockDim.x + threadIdx.x;
  const float* src = x;
  unsigned char* dst = xq;
  int i = idx;
  if (idx >= per_mat) { src = y; dst = yq; i = idx - per_mat; }
  float4 a = ((const float4*)src)[2 * (size_t)i];
  float4 b = ((const float4*)src)[2 * (size_t)i + 1];
  int v0 = 0, v1 = 0;
  v0 = __builtin_amdgcn_cvt_pk_fp8_f32(a.x * kQuantScale, a.y * kQuantScale, v0, false);
  v0 = __builtin_amdgcn_cvt_pk_fp8_f32(a.z * kQuantScale, a.w * kQuantScale, v0, true);
  v1 = __builtin_amdgcn_cvt_pk_fp8_f32(b.x * kQuantScale, b.y * kQuantScale, v1, false);
  v1 = __builtin_amdgcn_cvt_pk_fp8_f32(b.z * kQuantScale, b.w * kQuantScale, v1, true);
  *(int2*)(dst + (size_t)i * 8) = make_int2(v0, v1);   // plain row-major
}

// ---------------- persistent fused GEMM(MX-fp8) + exp + row-sum + finalize -----
// R26 = R17 conveyor with A-FRAGMENTS IN VGPRs (single-variable experiment).
// Evidence chain: R17 (45 us) is the best measured structure; all re-pacing
// variants (R18/R19/R21/R22/R23/R25) were neutral or worse. R18's A-hoist
// regression was diagnosed as AGPR placement (VGPR fell to 120 => compiler
// parked a8r in AGPRs, per-use copies). R26 retries the hoist with:
//  (a) A loaded DIRECTLY FROM GLOBAL (R24-verified load pattern: lane l15 =
//      row, quad*32 = byte window of the kb's 128B K-chunk) — no LDS trip;
//  (b) asm volatile("" : "+v") pinning each a8r to the VGPR class.
// Consequences: Xs eliminated (LDS 128K -> 64K), per-round LDS reads halve
// (32 -> 16 b128 per wave), and the A lgkm dependency leaves the round
// critical path: round = {stage Y(tt+1); read b8 x16; 32 MFMA; epilogue}.
// B staging/dbuf, swizzle, epilogue, diag mapping, finalize: R17 VERBATIM.
__global__ __launch_bounds__(512, 1)
void infonce_gemm(const unsigned char* __restrict__ X,
                  const unsigned char* __restrict__ Y,
                  float* __restrict__ rowsum, float* __restrict__ diag,
                  unsigned int* __restrict__ done, float* __restrict__ out) {
  __shared__ unsigned char Ys[2][128 * 256];   // 2 x 32 KB, Y tile dbuf (only LDS)
  __shared__ unsigned int ticket_s;

  const int b  = blockIdx.x;        // 0..255
  const int bi = b >> 3;            // 0..31: X-row-block (256 rows)
  const int gj = b & 7;             // col-group: col-tile ct = gj*8 + tt

  const int t    = threadIdx.x;
  const int lane = t & 63;
  const int wave = t >> 6;        // 0..7
  const int wm   = wave >> 1;     // 0..3  (64-row band)
  const int wn   = wave & 1;      // 0..1  (64-col half)
  const int quad = lane >> 4;     // 0..3
  const int l15  = lane & 15;

  const unsigned char* Xblk = X + (size_t)(bi * 256) * D_DIM;

  // ---- A fragments: global -> VGPR, once, pinned to 'v' class ----
  // (load pattern verified in R24: row = mt*16+l15 within the wave's 64-row
  //  band, 32B window = kb*128 + quad*32 of the row's 256B.)
  i32x8 a8r[2][4];
#pragma unroll
  for (int kb = 0; kb < 2; ++kb) {
#pragma unroll
    for (int mt = 0; mt < 4; ++mt) {
      const size_t off = (size_t)(wm * 64 + mt * 16 + l15) * D_DIM + kb * 128 + quad * 32;
      i32x4 lo = *(const i32x4*)(Xblk + off);
      i32x4 hi = *(const i32x4*)(Xblk + off + 16);
      a8r[kb][mt] = __builtin_shufflevector(lo, hi, 0, 1, 2, 3, 4, 5, 6, 7);
      asm volatile("" : "+v"(a8r[kb][mt]));   // pin to VGPR (anti-AGPR, anti-remat)
    }
  }

  // ---- stage Y tile 0 (2048 slots of 16B, 4 per thread) into buffer 0 ----
  {
    const unsigned char* Yblk = Y + (size_t)(gj * 8) * 128 * D_DIM;
#pragma unroll
    for (int it = 0; it < 4; ++it) {
      const int c0  = (it * 8 + wave) * 64;
      const int s   = c0 + lane;
      const int row = s >> 4;                 // 0..127
      const int cg  = (s & 15) ^ (row & 15);  // inverse swizzle on global side
      gl_lds16(Yblk + (size_t)row * D_DIM + cg * 16, &Ys[0][c0 * 16]);
    }
  }

  f32x4 acc[4][4];
#pragma unroll
  for (int a = 0; a < 4; ++a)
#pragma unroll
    for (int c = 0; c < 4; ++c) acc[a][c] = (f32x4){0.f, 0.f, 0.f, 0.f};

  float psum[4][4];   // per-lane running row-sum partials (over this lane's cols)
#pragma unroll
  for (int a = 0; a < 4; ++a)
#pragma unroll
    for (int c = 0; c < 4; ++c) psum[a][c] = 0.f;

  for (int tt = 0; tt < 8; ++tt) {
    const int p = tt & 1;

    __syncthreads();   // round tt staged (vmcnt drained by barrier)

    if (tt < 7) {      // stage Y tile tt+1 into the other buffer
      const unsigned char* Yblk = Y + (size_t)(gj * 8 + tt + 1) * 128 * D_DIM;
#pragma unroll
      for (int it = 0; it < 4; ++it) {
        const int c0  = (it * 8 + wave) * 64;
        const int s   = c0 + lane;
        const int row = s >> 4;
        const int cg  = (s & 15) ^ (row & 15);
        gl_lds16(Yblk + (size_t)row * D_DIM + cg * 16, &Ys[p ^ 1][c0 * 16]);
      }
    }

    // full-K compute: 2 MX k-blocks of 128; per kb: 8 B-frag b128 reads + 16
    // MFMA; A fragments already resident in VGPRs (no A LDS reads at all).
#pragma unroll
    for (int kb = 0; kb < 2; ++kb) {
      i32x8 b8[4];
#pragma unroll
      for (int nt = 0; nt < 4; ++nt) {
        const int row = wn * 64 + nt * 16 + l15;
        const int p0  = (kb * 8 + quad * 2 + 0) ^ (row & 15);
        const int p1  = (kb * 8 + quad * 2 + 1) ^ (row & 15);
        i32x4 lo = *(const i32x4*)(&Ys[p][row * 256 + p0 * 16]);
        i32x4 hi = *(const i32x4*)(&Ys[p][row * 256 + p1 * 16]);
        b8[nt] = __builtin_shufflevector(lo, hi, 0, 1, 2, 3, 4, 5, 6, 7);
      }
#pragma unroll
      for (int mt = 0; mt < 4; ++mt)
#pragma unroll
        for (int nt = 0; nt < 4; ++nt)
          acc[mt][nt] = __builtin_amdgcn_mfma_scale_f32_16x16x128_f8f6f4(
              a8r[kb][mt], b8[nt], acc[mt][nt],
              0, 0,                    // cbsz=fp8 e4m3, blgp=fp8 e4m3
              0, 0x7F7F7F7F,           // A scales = 1.0 (E8M0 127)
              0, 0x7F7F7F7F);          // B scales = 1.0
    }

    // ---- epilogue (R17 verbatim): exp + accumulate into registers ----
#pragma unroll
    for (int mt = 0; mt < 4; ++mt) {
#pragma unroll
      for (int rr = 0; rr < 4; ++rr) {
        float part = 0.f;
#pragma unroll
        for (int nt = 0; nt < 4; ++nt)
          part += __builtin_amdgcn_exp2f(acc[mt][nt][rr] * kScaleAcc);
        psum[mt][rr] += part;
      }
    }
    // diagonal: col-tile ct overlaps rows iff ct==2*bi (wm==wn) or 2*bi+1
    // (wm==wn+2). Device-scope atomicExch so the finalizer reads coherently.
    {
      const int ct = gj * 8 + tt;
      const bool d0 = (ct == 2 * bi)     && (wm == wn);
      const bool d1 = (ct == 2 * bi + 1) && (wm == wn + 2);
      if (d0 || d1) {
        const int gi_base = bi * 256 + wm * 64;
#pragma unroll
        for (int nt = 0; nt < 4; ++nt)
#pragma unroll
          for (int rr = 0; rr < 4; ++rr)
            if (l15 == quad * 4 + rr)
              atomicExch(&diag[gi_base + nt * 16 + l15], acc[nt][nt][rr]);
      }
    }
#pragma unroll
    for (int a = 0; a < 4; ++a)
#pragma unroll
      for (int c = 0; c < 4; ++c) acc[a][c] = (f32x4){0.f, 0.f, 0.f, 0.f};
  }

  // ---- one reduce + flush per block (16 shfl-chains + 16 atomics per wave) ----
  {
    const int gi_base = bi * 256 + wm * 64;
#pragma unroll
    for (int mt = 0; mt < 4; ++mt) {
#pragma unroll
      for (int rr = 0; rr < 4; ++rr) {
        float v = psum[mt][rr];
        v += __shfl_xor(v, 1);
        v += __shfl_xor(v, 2);
        v += __shfl_xor(v, 4);
        v += __shfl_xor(v, 8);
        if (l15 == 0)
          atomicAdd(&rowsum[gi_base + mt * 16 + quad * 4 + rr], v);
      }
    }
  }

  // ---- last-block finalize (single fence, single ticket — R15-proven) ----
  __syncthreads();                       // drains this block's atomics (vmcnt)
  if (t == 0) ticket_s = atomicAdd(&done[0], 1u);
  __syncthreads();
  if (ticket_s == 255u) {
    __threadfence();                     // one acquire, one block only
    float local = 0.f;
    for (int i = t; i < N_ROWS; i += 512) {
      const float rs = atomicAdd(&rowsum[i], 0.0f);   // device-coherent read
      const float d  = atomicAdd(&diag[i], 0.0f);
      local += __logf(rs - __builtin_amdgcn_exp2f(d * kScaleAcc)) - d * kInvTAcc;
    }
    float* red = (float*)Ys;             // Ys dead after last round; reuse
    red[t] = local;
    __syncthreads();
    for (int s2 = 256; s2 > 0; s2 >>= 1) {
      if (t < s2) red[t] += red[t + s2];
      __syncthreads();
    }
    if (t == 0) out[0] = red[0] / (float)N_ROWS;
  }
}

extern "C" void kernel_launch(void* const* d_in, const int* in_sizes, int n_in,
                              void* d_out, int out_size, void* d_ws, size_t ws_size,
                              hipStream_t stream) {
  const float* x = (const float*)d_in[0];
  const float* y = (const float*)d_in[1];
  float* out = (float*)d_out;

  // ws layout: rowsum[N] f32 | diag[N] f32 | done[32] u32 (128 B) | xq | yq
  float* rowsum = (float*)d_ws;
  float* diag   = rowsum + N_ROWS;
  unsigned int* done = (unsigned int*)(diag + N_ROWS);
  unsigned char* xq = (unsigned char*)d_ws + 2 * N_ROWS * sizeof(float) + 128;
  unsigned char* yq = xq + (size_t)N_ROWS * D_DIM;

  int cvt_blocks = 2 * N_ROWS * D_DIM / 8 / 256;  // 2048
  cvt_fp8_kernel<<<cvt_blocks, 256, 0, stream>>>(x, y, xq, yq, rowsum, done, out);

  infonce_gemm<<<256, 512, 0, stream>>>(xq, yq, rowsum, diag, done, out);
}